// Round 3
// baseline (833.227 us; speedup 1.0000x reference)
//
#include <hip/hip_runtime.h>

#define DMODEL 512
#define LSEQ   512
#define BATCH  4
#define NTOK   2048   // BATCH*LSEQ

typedef __attribute__((ext_vector_type(8))) short bf8;
typedef __attribute__((ext_vector_type(4))) float f4;
typedef __attribute__((ext_vector_type(4))) unsigned short us4;

__device__ __forceinline__ unsigned short bf16_rne(float f) {
  unsigned int u = __float_as_uint(f);
  u += 0x7FFFu + ((u >> 16) & 1u);
  return (unsigned short)(u >> 16);
}
__device__ __forceinline__ void split2(float f, unsigned short& h, unsigned short& l) {
  unsigned short hh = bf16_rne(f);
  float fh = __uint_as_float(((unsigned int)hh) << 16);
  h = hh;
  l = bf16_rne(f - fh);
}

// ---------------- LayerNorm over q -> bf16 hi/lo ----------------
__global__ __launch_bounds__(256) void ln_kernel(const float* __restrict__ q,
    const float* __restrict__ gamma, const float* __restrict__ beta,
    unsigned short* __restrict__ qh, unsigned short* __restrict__ qlo) {
  int row = blockIdx.x;
  const float* x = q + (size_t)row * DMODEL;
  int t = threadIdx.x;
  float v0 = x[t];
  float v1 = x[t + 256];
  float s  = v0 + v1;
  float ss = v0 * v0 + v1 * v1;
  #pragma unroll
  for (int o = 32; o >= 1; o >>= 1) {
    s  += __shfl_down(s, o);
    ss += __shfl_down(ss, o);
  }
  __shared__ float ls[4], lss[4];
  __shared__ float smu, srstd;
  int wid = t >> 6, lane = t & 63;
  if (lane == 0) { ls[wid] = s; lss[wid] = ss; }
  __syncthreads();
  if (t == 0) {
    float S  = ls[0] + ls[1] + ls[2] + ls[3];
    float SS = lss[0] + lss[1] + lss[2] + lss[3];
    float mu  = S * (1.0f / DMODEL);
    float var = SS * (1.0f / DMODEL) - mu * mu;
    smu = mu;
    srstd = rsqrtf(var + 1e-6f);
  }
  __syncthreads();
  float mu = smu, rstd = srstd;
  float n0 = (v0 - mu) * rstd * gamma[t]       + beta[t];
  float n1 = (v1 - mu) * rstd * gamma[t + 256] + beta[t + 256];
  unsigned short h, l;
  size_t base = (size_t)row * DMODEL;
  split2(n0, h, l); qh[base + t] = h;       qlo[base + t] = l;
  split2(n1, h, l); qh[base + t + 256] = h; qlo[base + t + 256] = l;
}

// ---------------- fp32 -> bf16 hi/lo converter (k, v, 4 weight mats) ----------------
__global__ __launch_bounds__(256) void conv_kernel(
    const float* __restrict__ k, const float* __restrict__ v,
    const float* __restrict__ Wq, const float* __restrict__ Wk,
    const float* __restrict__ Wv, const float* __restrict__ Wf,
    unsigned short* __restrict__ kh, unsigned short* __restrict__ kl,
    unsigned short* __restrict__ vh, unsigned short* __restrict__ vl,
    unsigned short* __restrict__ Wqh, unsigned short* __restrict__ Wql,
    unsigned short* __restrict__ Wkh, unsigned short* __restrict__ Wkl,
    unsigned short* __restrict__ Wvh, unsigned short* __restrict__ Wvl,
    unsigned short* __restrict__ Wfh, unsigned short* __restrict__ Wfl) {
  const float* src; unsigned short* dh; unsigned short* dl; int n;
  switch (blockIdx.y) {
    case 0:  src = k;  dh = kh;  dl = kl;  n = NTOK * DMODEL; break;
    case 1:  src = v;  dh = vh;  dl = vl;  n = NTOK * DMODEL; break;
    case 2:  src = Wq; dh = Wqh; dl = Wql; n = DMODEL * DMODEL; break;
    case 3:  src = Wk; dh = Wkh; dl = Wkl; n = DMODEL * DMODEL; break;
    case 4:  src = Wv; dh = Wvh; dl = Wvl; n = DMODEL * DMODEL; break;
    default: src = Wf; dh = Wfh; dl = Wfl; n = DMODEL * DMODEL; break;
  }
  int idx = blockIdx.x * 1024 + threadIdx.x * 4;
  if (idx >= n) return;
  float4 f = *(const float4*)(src + idx);
  us4 oh, ol;
  unsigned short h, l;
  split2(f.x, h, l); oh[0] = h; ol[0] = l;
  split2(f.y, h, l); oh[1] = h; ol[1] = l;
  split2(f.z, h, l); oh[2] = h; ol[2] = l;
  split2(f.w, h, l); oh[3] = h; ol[3] = l;
  *(us4*)(dh + idx) = oh;
  *(us4*)(dl + idx) = ol;
}

// ---------------- bf16x3 MFMA GEMM: C[M,N] = A[M,K] * W[N,K]^T ----------------
// block 256 = 4 waves (2x2), wave tile 32x32 via 2x2 of 16x16x32 MFMA. K=512.
__device__ __forceinline__ void mfma_gemm_body(
    const unsigned short* __restrict__ Ah, const unsigned short* __restrict__ Al,
    const unsigned short* __restrict__ Wh, const unsigned short* __restrict__ Wl,
    float* __restrict__ C, const float* __restrict__ bias, const float* __restrict__ resid) {
  const int t = threadIdx.x;
  const int w = t >> 6, lane = t & 63;
  const int wm = w >> 1, wn = w & 1;
  const int r0 = blockIdx.y * 64 + wm * 32;
  const int c0 = blockIdx.x * 64 + wn * 32;
  const int lr = lane & 15, quad = lane >> 4;
  f4 acc[2][2] = {};
  for (int k0 = 0; k0 < DMODEL; k0 += 32) {
    const int ko = k0 + quad * 8;
    bf8 ah[2], al[2], bh[2], bl[2];
    #pragma unroll
    for (int mi = 0; mi < 2; mi++) {
      const size_t off = (size_t)(r0 + mi * 16 + lr) * DMODEL + ko;
      ah[mi] = *(const bf8*)(Ah + off);
      al[mi] = *(const bf8*)(Al + off);
    }
    #pragma unroll
    for (int ni = 0; ni < 2; ni++) {
      const size_t off = (size_t)(c0 + ni * 16 + lr) * DMODEL + ko;
      bh[ni] = *(const bf8*)(Wh + off);
      bl[ni] = *(const bf8*)(Wl + off);
    }
    #pragma unroll
    for (int mi = 0; mi < 2; mi++)
      #pragma unroll
      for (int ni = 0; ni < 2; ni++) {
        acc[mi][ni] = __builtin_amdgcn_mfma_f32_16x16x32_bf16(al[mi], bh[ni], acc[mi][ni], 0, 0, 0);
        acc[mi][ni] = __builtin_amdgcn_mfma_f32_16x16x32_bf16(ah[mi], bl[ni], acc[mi][ni], 0, 0, 0);
        acc[mi][ni] = __builtin_amdgcn_mfma_f32_16x16x32_bf16(ah[mi], bh[ni], acc[mi][ni], 0, 0, 0);
      }
  }
  #pragma unroll
  for (int mi = 0; mi < 2; mi++)
    #pragma unroll
    for (int ni = 0; ni < 2; ni++)
      #pragma unroll
      for (int r = 0; r < 4; r++) {
        int row = r0 + mi * 16 + quad * 4 + r;   // C/D: col=lane&15, row=quad*4+reg (m89)
        int col = c0 + ni * 16 + lr;
        float o = acc[mi][ni][r];
        if (bias)  o += bias[col];
        if (resid) o += resid[(size_t)row * DMODEL + col];
        C[(size_t)row * DMODEL + col] = o;
      }
}

__global__ __launch_bounds__(256) void proj_mfma(
    const unsigned short* __restrict__ qnh, const unsigned short* __restrict__ qnl,
    const unsigned short* __restrict__ kh, const unsigned short* __restrict__ kl,
    const unsigned short* __restrict__ vh, const unsigned short* __restrict__ vl,
    const unsigned short* __restrict__ Wqh, const unsigned short* __restrict__ Wql,
    const unsigned short* __restrict__ Wkh, const unsigned short* __restrict__ Wkl,
    const unsigned short* __restrict__ Wvh, const unsigned short* __restrict__ Wvl,
    float* __restrict__ Qp, float* __restrict__ Kp, float* __restrict__ Vp) {
  const unsigned short *Ah, *Al, *Wh, *Wl; float* C;
  if (blockIdx.z == 0)      { Ah = qnh; Al = qnl; Wh = Wqh; Wl = Wql; C = Qp; }
  else if (blockIdx.z == 1) { Ah = kh;  Al = kl;  Wh = Wkh; Wl = Wkl; C = Kp; }
  else                      { Ah = vh;  Al = vl;  Wh = Wvh; Wl = Wvl; C = Vp; }
  mfma_gemm_body(Ah, Al, Wh, Wl, C, nullptr, nullptr);
}

__global__ __launch_bounds__(256) void fc_mfma(
    const unsigned short* __restrict__ AOh, const unsigned short* __restrict__ AOl,
    const unsigned short* __restrict__ Wfh, const unsigned short* __restrict__ Wfl,
    const float* __restrict__ bfc, const float* __restrict__ resid,
    float* __restrict__ out) {
  mfma_gemm_body(AOh, AOl, Wfh, Wfl, out, bfc, resid);
}

// Multi-value butterfly reduce: 8 per-lane feature accumulators -> full 64-lane sums
// in 10 shuffles. Combine order per feature is the identical xor 1,2,4,8,16,32 ladder
// as a per-feature reduce -> bit-identical results.
// Final: every lane holds the sum for feature f = ((lane&1)<<2)|(lane&2)|((lane>>2)&1).
__device__ __forceinline__ float pv_reduce8(float pv[8], int lane) {
  #pragma unroll
  for (int i = 0; i < 4; i++) {
    float sendv = (lane & 1) ? pv[i] : pv[i + 4];
    float recv = __shfl_xor(sendv, 1);
    pv[i] = ((lane & 1) ? pv[i + 4] : pv[i]) + recv;
  }
  #pragma unroll
  for (int i = 0; i < 2; i++) {
    float sendv = (lane & 2) ? pv[i] : pv[i + 2];
    float recv = __shfl_xor(sendv, 2);
    pv[i] = ((lane & 2) ? pv[i + 2] : pv[i]) + recv;
  }
  {
    float sendv = (lane & 4) ? pv[0] : pv[1];
    float recv = __shfl_xor(sendv, 4);
    pv[0] = ((lane & 4) ? pv[1] : pv[0]) + recv;
  }
  pv[0] += __shfl_xor(pv[0], 8);
  pv[0] += __shfl_xor(pv[0], 16);
  pv[0] += __shfl_xor(pv[0], 32);
  return pv[0];
}

// ---------------- attention per (b, dk): K in regs, V in LDS ----------------
// grid (8 qtiles x 64 dk x 4 b); block 256 = 4 waves; wave handles 16 q rows,
// processed as 8 PAIRS for ILP (two independent softmax/reduce chains in flight,
// V LDS reads shared between the pair). Plain (cached) loads/stores — the 256MB
// L3 absorbs a large part of the sim/attn streams (round-1 lesson: NT hints
// quadrupled HBM fetch).
__global__ __launch_bounds__(256, 3) void attn2_kernel(
    const float* __restrict__ Qp, const float* __restrict__ Kp, const float* __restrict__ Vp,
    const float* __restrict__ sim, float* __restrict__ attn_out,
    unsigned short* __restrict__ AOh, unsigned short* __restrict__ AOl) {
  __shared__ float Vt[8][516];   // padded: conflict-free staging writes, aligned b128 reads
  __shared__ float Qs[64][8];
  const int qt = blockIdx.x, dk = blockIdx.y, b = blockIdx.z;
  const int t = threadIdx.x;
  const float* Vbase = Vp + (size_t)b * LSEQ * DMODEL + dk * 8;
  #pragma unroll
  for (int it = 0; it < 16; it++) {
    int idx = it * 256 + t;
    int l = idx >> 3, j = idx & 7;
    Vt[j][l] = Vbase[(size_t)l * DMODEL + j];
  }
  const float* Qbase = Qp + ((size_t)b * LSEQ + qt * 64) * DMODEL + dk * 8;
  #pragma unroll
  for (int it = 0; it < 2; it++) {
    int idx = it * 256 + t;
    int l = idx >> 3, j = idx & 7;
    Qs[l][j] = Qbase[(size_t)l * DMODEL + j];
  }
  const int lane = t & 63, w = t >> 6;
  const float* Kbase = Kp + (size_t)b * LSEQ * DMODEL + dk * 8;
  float Kr[2][8][4];                         // [chunk][feature][sub]: kp = c*256 + lane*4 + s
  #pragma unroll
  for (int c = 0; c < 2; c++)
    #pragma unroll
    for (int s = 0; s < 4; s++) {
      const float* kr = Kbase + (size_t)(c * 256 + lane * 4 + s) * DMODEL;
      float4 a  = *(const float4*)kr;
      float4 bb = *(const float4*)(kr + 4);
      Kr[c][0][s] = a.x;  Kr[c][1][s] = a.y;  Kr[c][2][s] = a.z;  Kr[c][3][s] = a.w;
      Kr[c][4][s] = bb.x; Kr[c][5][s] = bb.y; Kr[c][6][s] = bb.z; Kr[c][7][s] = bb.w;
    }
  __syncthreads();

  for (int qp = 0; qp < 8; qp++) {
    const int qlA = w * 16 + qp * 2;
    const int qA = qt * 64 + qlA;
    const size_t rowA = (((size_t)(b * 64 + dk) * LSEQ) + qA) * LSEQ;
    const size_t rowB = rowA + LSEQ;
    // issue all 4 sim loads up front (plain, cached)
    f4 sA0 = *(const f4*)(sim + rowA + lane * 4);
    f4 sA1 = *(const f4*)(sim + rowA + 256 + lane * 4);
    f4 sB0 = *(const f4*)(sim + rowB + lane * 4);
    f4 sB1 = *(const f4*)(sim + rowB + 256 + lane * 4);
    // Q rows (LDS broadcast, vectorized)
    f4 qa0 = *(const f4*)&Qs[qlA][0],     qa1 = *(const f4*)&Qs[qlA][4];
    f4 qb0 = *(const f4*)&Qs[qlA + 1][0], qb1 = *(const f4*)&Qs[qlA + 1][4];
    // scores (overlaps with sim loads in flight)
    float scA[2][4], scB[2][4];
    #pragma unroll
    for (int c = 0; c < 2; c++)
      #pragma unroll
      for (int s = 0; s < 4; s++) {
        float dA = 0.0f, dB = 0.0f;
        #pragma unroll
        for (int j = 0; j < 4; j++) {
          dA = fmaf(qa0[j], Kr[c][j][s], dA);
          dB = fmaf(qb0[j], Kr[c][j][s], dB);
        }
        #pragma unroll
        for (int j = 0; j < 4; j++) {
          dA = fmaf(qa1[j], Kr[c][j + 4][s], dA);
          dB = fmaf(qb1[j], Kr[c][j + 4][s], dB);
        }
        scA[c][s] = fmaf(dA, 0.125f, (c ? sA1 : sA0)[s]);
        scB[c][s] = fmaf(dB, 0.125f, (c ? sB1 : sB0)[s]);
      }
    // softmax: two independent chains interleave
    float mA = scA[0][0], mB = scB[0][0];
    #pragma unroll
    for (int c = 0; c < 2; c++)
      #pragma unroll
      for (int s = 0; s < 4; s++) { mA = fmaxf(mA, scA[c][s]); mB = fmaxf(mB, scB[c][s]); }
    #pragma unroll
    for (int o = 1; o < 64; o <<= 1) {
      mA = fmaxf(mA, __shfl_xor(mA, o));
      mB = fmaxf(mB, __shfl_xor(mB, o));
    }
    float pA[2][4], pB[2][4];
    float sumA = 0.0f, sumB = 0.0f;
    #pragma unroll
    for (int c = 0; c < 2; c++)
      #pragma unroll
      for (int s = 0; s < 4; s++) {
        pA[c][s] = __expf(scA[c][s] - mA); sumA += pA[c][s];
        pB[c][s] = __expf(scB[c][s] - mB); sumB += pB[c][s];
      }
    #pragma unroll
    for (int o = 1; o < 64; o <<= 1) {
      sumA += __shfl_xor(sumA, o);
      sumB += __shfl_xor(sumB, o);
    }
    const float rA = 1.0f / sumA, rB = 1.0f / sumB;
    #pragma unroll
    for (int c = 0; c < 2; c++)
      #pragma unroll
      for (int s = 0; s < 4; s++) { pA[c][s] *= rA; pB[c][s] *= rB; }
    // attn output (plain cached stores)
    f4 stA0 = {pA[0][0], pA[0][1], pA[0][2], pA[0][3]};
    f4 stA1 = {pA[1][0], pA[1][1], pA[1][2], pA[1][3]};
    f4 stB0 = {pB[0][0], pB[0][1], pB[0][2], pB[0][3]};
    f4 stB1 = {pB[1][0], pB[1][1], pB[1][2], pB[1][3]};
    *(f4*)(attn_out + rowA + lane * 4) = stA0;
    *(f4*)(attn_out + rowA + 256 + lane * 4) = stA1;
    *(f4*)(attn_out + rowB + lane * 4) = stB0;
    *(f4*)(attn_out + rowB + 256 + lane * 4) = stB1;
    // PV: each V b128 read feeds BOTH rows of the pair
    float pvA[8], pvB[8];
    #pragma unroll
    for (int j = 0; j < 8; j++) {
      f4 v0 = *(const f4*)&Vt[j][lane * 4];
      f4 v1 = *(const f4*)&Vt[j][256 + lane * 4];
      float aA = 0.0f, aB = 0.0f;
      #pragma unroll
      for (int s = 0; s < 4; s++) {
        aA = fmaf(pA[0][s], v0[s], aA);
        aB = fmaf(pB[0][s], v0[s], aB);
      }
      #pragma unroll
      for (int s = 0; s < 4; s++) {
        aA = fmaf(pA[1][s], v1[s], aA);
        aB = fmaf(pB[1][s], v1[s], aB);
      }
      pvA[j] = aA; pvB[j] = aB;
    }
    float outA = pv_reduce8(pvA, lane);
    float outB = pv_reduce8(pvB, lane);
    // AO write: lanes 0-7 write hi, lanes 8-15 write lo; feature from butterfly layout
    if (lane < 16) {
      const int j = ((lane & 1) << 2) | (lane & 2) | ((lane >> 2) & 1);
      const size_t baseA = ((size_t)b * LSEQ + qA) * DMODEL + dk * 8 + j;
      unsigned short hA, loA, hB, loB;
      split2(outA, hA, loA);
      split2(outB, hB, loB);
      if (lane < 8) { AOh[baseA] = hA;  AOh[baseA + DMODEL] = hB; }
      else          { AOl[baseA] = loA; AOl[baseA + DMODEL] = loB; }
    }
  }
}

extern "C" void kernel_launch(void* const* d_in, const int* in_sizes, int n_in,
                              void* d_out, int out_size, void* d_ws, size_t ws_size,
                              hipStream_t stream) {
  const float* q    = (const float*)d_in[0];
  const float* k    = (const float*)d_in[1];
  const float* v    = (const float*)d_in[2];
  const float* sim  = (const float*)d_in[3];
  const float* Wq   = (const float*)d_in[4];
  const float* Wk   = (const float*)d_in[5];
  const float* Wv   = (const float*)d_in[6];
  const float* Wfc  = (const float*)d_in[7];
  const float* bfc  = (const float*)d_in[8];
  const float* ln_g = (const float*)d_in[9];
  const float* ln_b = (const float*)d_in[10];

  float* out  = (float*)d_out;                          // [B,L,DM] (also holds Qp until fc)
  float* attn = out + (size_t)NTOK * DMODEL;            // [B,64,L,L]

  // scratch inside attn region (dead before attn2 writes it): k/v bf16 hi/lo
  unsigned short* kh = (unsigned short*)attn;
  unsigned short* kl = kh + (size_t)NTOK * DMODEL;
  unsigned short* vh = kl + (size_t)NTOK * DMODEL;
  unsigned short* vl = vh + (size_t)NTOK * DMODEL;
  float* Qp = out;                                      // out region reused; fc overwrites at end

  // ws layout: qn hi/lo (reused as AO hi/lo), W hi/lo x4, Kp, Vp  = 16 MB
  unsigned short* qnh = (unsigned short*)d_ws;
  unsigned short* qnl = qnh + (size_t)NTOK * DMODEL;
  unsigned short* Wqh = qnl + (size_t)NTOK * DMODEL;
  unsigned short* Wql = Wqh + DMODEL * DMODEL;
  unsigned short* Wkh = Wql + DMODEL * DMODEL;
  unsigned short* Wkl = Wkh + DMODEL * DMODEL;
  unsigned short* Wvh = Wkl + DMODEL * DMODEL;
  unsigned short* Wvl = Wvh + DMODEL * DMODEL;
  unsigned short* Wfh = Wvl + DMODEL * DMODEL;
  unsigned short* Wfl = Wfh + DMODEL * DMODEL;
  float* Kp = (float*)(Wfl + DMODEL * DMODEL);
  float* Vp = Kp + (size_t)NTOK * DMODEL;
  unsigned short* AOh = qnh;   // qn dead after proj
  unsigned short* AOl = qnl;

  ln_kernel<<<dim3(NTOK), dim3(256), 0, stream>>>(q, ln_g, ln_b, qnh, qnl);
  conv_kernel<<<dim3(1024, 6), dim3(256), 0, stream>>>(k, v, Wq, Wk, Wv, Wfc,
      kh, kl, vh, vl, Wqh, Wql, Wkh, Wkl, Wvh, Wvl, Wfh, Wfl);
  proj_mfma<<<dim3(8, 32, 3), dim3(256), 0, stream>>>(qnh, qnl, kh, kl, vh, vl,
      Wqh, Wql, Wkh, Wkl, Wvh, Wvl, Qp, Kp, Vp);
  attn2_kernel<<<dim3(8, 64, 4), dim3(256), 0, stream>>>(Qp, Kp, Vp, sim, attn, AOh, AOl);
  fc_mfma<<<dim3(8, 32, 1), dim3(256), 0, stream>>>(AOh, AOl, Wfh, Wfl, bfc, q, out);
}

// Round 4
// 576.329 us; speedup vs baseline: 1.4457x; 1.4457x over previous
//
#include <hip/hip_runtime.h>

#define DMODEL 512
#define LSEQ   512
#define BATCH  4
#define NTOK   2048   // BATCH*LSEQ

typedef __attribute__((ext_vector_type(8))) short bf8;
typedef __attribute__((ext_vector_type(4))) float f4;
typedef __attribute__((ext_vector_type(4))) unsigned short us4;
typedef __attribute__((ext_vector_type(8))) unsigned short us8;

__device__ __forceinline__ unsigned short bf16_rne(float f) {
  unsigned int u = __float_as_uint(f);
  u += 0x7FFFu + ((u >> 16) & 1u);
  return (unsigned short)(u >> 16);
}
__device__ __forceinline__ void split2(float f, unsigned short& h, unsigned short& l) {
  unsigned short hh = bf16_rne(f);
  float fh = __uint_as_float(((unsigned int)hh) << 16);
  h = hh;
  l = bf16_rne(f - fh);
}

// ---------------- LayerNorm over q -> bf16 hi/lo ----------------
__global__ __launch_bounds__(256) void ln_kernel(const float* __restrict__ q,
    const float* __restrict__ gamma, const float* __restrict__ beta,
    unsigned short* __restrict__ qh, unsigned short* __restrict__ qlo) {
  int row = blockIdx.x;
  const float* x = q + (size_t)row * DMODEL;
  int t = threadIdx.x;
  float v0 = x[t];
  float v1 = x[t + 256];
  float s  = v0 + v1;
  float ss = v0 * v0 + v1 * v1;
  #pragma unroll
  for (int o = 32; o >= 1; o >>= 1) {
    s  += __shfl_down(s, o);
    ss += __shfl_down(ss, o);
  }
  __shared__ float ls[4], lss[4];
  __shared__ float smu, srstd;
  int wid = t >> 6, lane = t & 63;
  if (lane == 0) { ls[wid] = s; lss[wid] = ss; }
  __syncthreads();
  if (t == 0) {
    float S  = ls[0] + ls[1] + ls[2] + ls[3];
    float SS = lss[0] + lss[1] + lss[2] + lss[3];
    float mu  = S * (1.0f / DMODEL);
    float var = SS * (1.0f / DMODEL) - mu * mu;
    smu = mu;
    srstd = rsqrtf(var + 1e-6f);
  }
  __syncthreads();
  float mu = smu, rstd = srstd;
  float n0 = (v0 - mu) * rstd * gamma[t]       + beta[t];
  float n1 = (v1 - mu) * rstd * gamma[t + 256] + beta[t + 256];
  unsigned short h, l;
  size_t base = (size_t)row * DMODEL;
  split2(n0, h, l); qh[base + t] = h;       qlo[base + t] = l;
  split2(n1, h, l); qh[base + t + 256] = h; qlo[base + t + 256] = l;
}

// ---------------- fp32 -> bf16 hi/lo converter (k, v, 4 weight mats) ----------------
__global__ __launch_bounds__(256) void conv_kernel(
    const float* __restrict__ k, const float* __restrict__ v,
    const float* __restrict__ Wq, const float* __restrict__ Wk,
    const float* __restrict__ Wv, const float* __restrict__ Wf,
    unsigned short* __restrict__ kh, unsigned short* __restrict__ kl,
    unsigned short* __restrict__ vh, unsigned short* __restrict__ vl,
    unsigned short* __restrict__ Wqh, unsigned short* __restrict__ Wql,
    unsigned short* __restrict__ Wkh, unsigned short* __restrict__ Wkl,
    unsigned short* __restrict__ Wvh, unsigned short* __restrict__ Wvl,
    unsigned short* __restrict__ Wfh, unsigned short* __restrict__ Wfl) {
  const float* src; unsigned short* dh; unsigned short* dl; int n;
  switch (blockIdx.y) {
    case 0:  src = k;  dh = kh;  dl = kl;  n = NTOK * DMODEL; break;
    case 1:  src = v;  dh = vh;  dl = vl;  n = NTOK * DMODEL; break;
    case 2:  src = Wq; dh = Wqh; dl = Wql; n = DMODEL * DMODEL; break;
    case 3:  src = Wk; dh = Wkh; dl = Wkl; n = DMODEL * DMODEL; break;
    case 4:  src = Wv; dh = Wvh; dl = Wvl; n = DMODEL * DMODEL; break;
    default: src = Wf; dh = Wfh; dl = Wfl; n = DMODEL * DMODEL; break;
  }
  int idx = blockIdx.x * 1024 + threadIdx.x * 4;
  if (idx >= n) return;
  float4 f = *(const float4*)(src + idx);
  us4 oh, ol;
  unsigned short h, l;
  split2(f.x, h, l); oh[0] = h; ol[0] = l;
  split2(f.y, h, l); oh[1] = h; ol[1] = l;
  split2(f.z, h, l); oh[2] = h; ol[2] = l;
  split2(f.w, h, l); oh[3] = h; ol[3] = l;
  *(us4*)(dh + idx) = oh;
  *(us4*)(dl + idx) = ol;
}

// ---------------- bf16x3 MFMA GEMM: C[M,N] = A[M,K] * W[N,K]^T ----------------
// block 256 = 4 waves (2x2), wave tile 32x32 via 2x2 of 16x16x32 MFMA. K=512.
__device__ __forceinline__ void mfma_gemm_body(
    const unsigned short* __restrict__ Ah, const unsigned short* __restrict__ Al,
    const unsigned short* __restrict__ Wh, const unsigned short* __restrict__ Wl,
    float* __restrict__ C, const float* __restrict__ bias, const float* __restrict__ resid) {
  const int t = threadIdx.x;
  const int w = t >> 6, lane = t & 63;
  const int wm = w >> 1, wn = w & 1;
  const int r0 = blockIdx.y * 64 + wm * 32;
  const int c0 = blockIdx.x * 64 + wn * 32;
  const int lr = lane & 15, quad = lane >> 4;
  f4 acc[2][2] = {};
  for (int k0 = 0; k0 < DMODEL; k0 += 32) {
    const int ko = k0 + quad * 8;
    bf8 ah[2], al[2], bh[2], bl[2];
    #pragma unroll
    for (int mi = 0; mi < 2; mi++) {
      const size_t off = (size_t)(r0 + mi * 16 + lr) * DMODEL + ko;
      ah[mi] = *(const bf8*)(Ah + off);
      al[mi] = *(const bf8*)(Al + off);
    }
    #pragma unroll
    for (int ni = 0; ni < 2; ni++) {
      const size_t off = (size_t)(c0 + ni * 16 + lr) * DMODEL + ko;
      bh[ni] = *(const bf8*)(Wh + off);
      bl[ni] = *(const bf8*)(Wl + off);
    }
    #pragma unroll
    for (int mi = 0; mi < 2; mi++)
      #pragma unroll
      for (int ni = 0; ni < 2; ni++) {
        acc[mi][ni] = __builtin_amdgcn_mfma_f32_16x16x32_bf16(al[mi], bh[ni], acc[mi][ni], 0, 0, 0);
        acc[mi][ni] = __builtin_amdgcn_mfma_f32_16x16x32_bf16(ah[mi], bl[ni], acc[mi][ni], 0, 0, 0);
        acc[mi][ni] = __builtin_amdgcn_mfma_f32_16x16x32_bf16(ah[mi], bh[ni], acc[mi][ni], 0, 0, 0);
      }
  }
  #pragma unroll
  for (int mi = 0; mi < 2; mi++)
    #pragma unroll
    for (int ni = 0; ni < 2; ni++)
      #pragma unroll
      for (int r = 0; r < 4; r++) {
        int row = r0 + mi * 16 + quad * 4 + r;   // C/D: col=lane&15, row=quad*4+reg (m89)
        int col = c0 + ni * 16 + lr;
        float o = acc[mi][ni][r];
        if (bias)  o += bias[col];
        if (resid) o += resid[(size_t)row * DMODEL + col];
        C[(size_t)row * DMODEL + col] = o;
      }
}

__global__ __launch_bounds__(256) void proj_mfma(
    const unsigned short* __restrict__ qnh, const unsigned short* __restrict__ qnl,
    const unsigned short* __restrict__ kh, const unsigned short* __restrict__ kl,
    const unsigned short* __restrict__ vh, const unsigned short* __restrict__ vl,
    const unsigned short* __restrict__ Wqh, const unsigned short* __restrict__ Wql,
    const unsigned short* __restrict__ Wkh, const unsigned short* __restrict__ Wkl,
    const unsigned short* __restrict__ Wvh, const unsigned short* __restrict__ Wvl,
    float* __restrict__ Qp, float* __restrict__ Kp, float* __restrict__ Vp) {
  const unsigned short *Ah, *Al, *Wh, *Wl; float* C;
  if (blockIdx.z == 0)      { Ah = qnh; Al = qnl; Wh = Wqh; Wl = Wql; C = Qp; }
  else if (blockIdx.z == 1) { Ah = kh;  Al = kl;  Wh = Wkh; Wl = Wkl; C = Kp; }
  else                      { Ah = vh;  Al = vl;  Wh = Wvh; Wl = Wvl; C = Vp; }
  mfma_gemm_body(Ah, Al, Wh, Wl, C, nullptr, nullptr);
}

__global__ __launch_bounds__(256) void fc_mfma(
    const unsigned short* __restrict__ AOh, const unsigned short* __restrict__ AOl,
    const unsigned short* __restrict__ Wfh, const unsigned short* __restrict__ Wfl,
    const float* __restrict__ bfc, const float* __restrict__ resid,
    float* __restrict__ out) {
  mfma_gemm_body(AOh, AOl, Wfh, Wfl, out, bfc, resid);
}

// Multi-value butterfly reduce: 8 per-lane feature accumulators -> full 64-lane sums
// in 10 shuffles. Combine order per feature is the identical xor 1,2,4,8,16,32 ladder
// as a per-feature reduce -> bit-identical results (validated Rounds 1/3, absmax same).
// Final: every lane holds the sum for feature f = ((lane&1)<<2)|(lane&2)|((lane>>2)&1).
__device__ __forceinline__ float pv_reduce8(float pv[8], int lane) {
  #pragma unroll
  for (int i = 0; i < 4; i++) {
    float sendv = (lane & 1) ? pv[i] : pv[i + 4];
    float recv = __shfl_xor(sendv, 1);
    pv[i] = ((lane & 1) ? pv[i + 4] : pv[i]) + recv;
  }
  #pragma unroll
  for (int i = 0; i < 2; i++) {
    float sendv = (lane & 2) ? pv[i] : pv[i + 2];
    float recv = __shfl_xor(sendv, 2);
    pv[i] = ((lane & 2) ? pv[i + 2] : pv[i]) + recv;
  }
  {
    float sendv = (lane & 4) ? pv[0] : pv[1];
    float recv = __shfl_xor(sendv, 4);
    pv[0] = ((lane & 4) ? pv[1] : pv[0]) + recv;
  }
  pv[0] += __shfl_xor(pv[0], 8);
  pv[0] += __shfl_xor(pv[0], 16);
  pv[0] += __shfl_xor(pv[0], 32);
  return pv[0];
}

// ---------------- attention per (b, dk): K in regs, V in LDS, vectorized sim/attn ----------------
// grid (8 qtiles x 64 dk x 4 b); block 256 = 4 waves; wave handles 16 q rows.
// Identical global access pattern to the verified 582us baseline; only the PV
// reduction is changed (48 shuffles -> 10-shuffle butterfly + in-wave LDS repack),
// final AO store is the same lane<2 us8 16B store.
__global__ __launch_bounds__(256, 3) void attn2_kernel(
    const float* __restrict__ Qp, const float* __restrict__ Kp, const float* __restrict__ Vp,
    const float* __restrict__ sim, float* __restrict__ attn_out,
    unsigned short* __restrict__ AOh, unsigned short* __restrict__ AOl) {
  __shared__ float Vt[8][516];   // padded: conflict-free staging writes, aligned b128 reads
  __shared__ float Qs[64][8];
  __shared__ float Rp[4][8];     // per-wave PV repack (wave-synchronous)
  const int qt = blockIdx.x, dk = blockIdx.y, b = blockIdx.z;
  const int t = threadIdx.x;
  const float* Vbase = Vp + (size_t)b * LSEQ * DMODEL + dk * 8;
  #pragma unroll
  for (int it = 0; it < 16; it++) {
    int idx = it * 256 + t;
    int l = idx >> 3, j = idx & 7;
    Vt[j][l] = Vbase[(size_t)l * DMODEL + j];
  }
  const float* Qbase = Qp + ((size_t)b * LSEQ + qt * 64) * DMODEL + dk * 8;
  #pragma unroll
  for (int it = 0; it < 2; it++) {
    int idx = it * 256 + t;
    int l = idx >> 3, j = idx & 7;
    Qs[l][j] = Qbase[(size_t)l * DMODEL + j];
  }
  const int lane = t & 63, w = t >> 6;
  const float* Kbase = Kp + (size_t)b * LSEQ * DMODEL + dk * 8;
  float Kr[2][8][4];                         // [chunk][feature][sub]: kp = c*256 + lane*4 + s
  #pragma unroll
  for (int c = 0; c < 2; c++)
    #pragma unroll
    for (int s = 0; s < 4; s++) {
      const float* kr = Kbase + (size_t)(c * 256 + lane * 4 + s) * DMODEL;
      float4 a  = *(const float4*)kr;
      float4 bb = *(const float4*)(kr + 4);
      Kr[c][0][s] = a.x;  Kr[c][1][s] = a.y;  Kr[c][2][s] = a.z;  Kr[c][3][s] = a.w;
      Kr[c][4][s] = bb.x; Kr[c][5][s] = bb.y; Kr[c][6][s] = bb.z; Kr[c][7][s] = bb.w;
    }
  __syncthreads();

  for (int qi = 0; qi < 16; qi++) {
    const int ql = w * 16 + qi;
    const int q  = qt * 64 + ql;
    const size_t rowoff = (((size_t)(b * 64 + dk) * LSEQ) + q) * LSEQ;
    float4 sv0 = *(const float4*)(sim + rowoff + lane * 4);
    float4 sv1 = *(const float4*)(sim + rowoff + 256 + lane * 4);
    float svf[2][4] = {{sv0.x, sv0.y, sv0.z, sv0.w}, {sv1.x, sv1.y, sv1.z, sv1.w}};
    float qreg[8];
    #pragma unroll
    for (int j = 0; j < 8; j++) qreg[j] = Qs[ql][j];   // LDS broadcast
    float sc[2][4];
    #pragma unroll
    for (int c = 0; c < 2; c++)
      #pragma unroll
      for (int s = 0; s < 4; s++) {
        float d = 0.0f;
        #pragma unroll
        for (int j = 0; j < 8; j++) d = fmaf(qreg[j], Kr[c][j][s], d);
        sc[c][s] = fmaf(d, 0.125f, svf[c][s]);
      }
    float m = sc[0][0];
    #pragma unroll
    for (int c = 0; c < 2; c++)
      #pragma unroll
      for (int s = 0; s < 4; s++) m = fmaxf(m, sc[c][s]);
    #pragma unroll
    for (int o = 1; o < 64; o <<= 1) m = fmaxf(m, __shfl_xor(m, o));
    float p[2][4]; float sum = 0.0f;
    #pragma unroll
    for (int c = 0; c < 2; c++)
      #pragma unroll
      for (int s = 0; s < 4; s++) { p[c][s] = __expf(sc[c][s] - m); sum += p[c][s]; }
    #pragma unroll
    for (int o = 1; o < 64; o <<= 1) sum += __shfl_xor(sum, o);
    const float r = 1.0f / sum;
    #pragma unroll
    for (int c = 0; c < 2; c++)
      #pragma unroll
      for (int s = 0; s < 4; s++) p[c][s] *= r;
    float4 st0 = {p[0][0], p[0][1], p[0][2], p[0][3]};
    float4 st1 = {p[1][0], p[1][1], p[1][2], p[1][3]};
    *(float4*)(attn_out + rowoff + lane * 4) = st0;
    *(float4*)(attn_out + rowoff + 256 + lane * 4) = st1;
    // PV
    float pv[8];
    #pragma unroll
    for (int j = 0; j < 8; j++) {
      float acc = 0.0f;
      #pragma unroll
      for (int c = 0; c < 2; c++) {
        float4 vv = *(const float4*)&Vt[j][c * 256 + lane * 4];
        acc = fmaf(p[c][0], vv.x, acc);
        acc = fmaf(p[c][1], vv.y, acc);
        acc = fmaf(p[c][2], vv.z, acc);
        acc = fmaf(p[c][3], vv.w, acc);
      }
      pv[j] = acc;
    }
    // 10-shuffle butterfly instead of 48 per-feature shuffles (bit-identical sums)
    float red = pv_reduce8(pv, lane);
    if (lane < 8)
      Rp[w][((lane & 1) << 2) | (lane & 2) | ((lane >> 2) & 1)] = red;
    __builtin_amdgcn_wave_barrier();   // in-wave LDS write->read ordering fence
    if (lane < 2) {
      us8 ov;
      #pragma unroll
      for (int j = 0; j < 8; j++) {
        unsigned short h, l;
        split2(Rp[w][j], h, l);
        ov[j] = (lane == 0) ? h : l;
      }
      unsigned short* dst = ((lane == 0) ? AOh : AOl) + ((size_t)b * LSEQ + q) * DMODEL + dk * 8;
      *(us8*)dst = ov;
    }
  }
}

extern "C" void kernel_launch(void* const* d_in, const int* in_sizes, int n_in,
                              void* d_out, int out_size, void* d_ws, size_t ws_size,
                              hipStream_t stream) {
  const float* q    = (const float*)d_in[0];
  const float* k    = (const float*)d_in[1];
  const float* v    = (const float*)d_in[2];
  const float* sim  = (const float*)d_in[3];
  const float* Wq   = (const float*)d_in[4];
  const float* Wk   = (const float*)d_in[5];
  const float* Wv   = (const float*)d_in[6];
  const float* Wfc  = (const float*)d_in[7];
  const float* bfc  = (const float*)d_in[8];
  const float* ln_g = (const float*)d_in[9];
  const float* ln_b = (const float*)d_in[10];

  float* out  = (float*)d_out;                          // [B,L,DM] (also holds Qp until fc)
  float* attn = out + (size_t)NTOK * DMODEL;            // [B,64,L,L]

  // scratch inside attn region (dead before attn2 writes it): k/v bf16 hi/lo
  unsigned short* kh = (unsigned short*)attn;
  unsigned short* kl = kh + (size_t)NTOK * DMODEL;
  unsigned short* vh = kl + (size_t)NTOK * DMODEL;
  unsigned short* vl = vh + (size_t)NTOK * DMODEL;
  float* Qp = out;                                      // out region reused; fc overwrites at end

  // ws layout: qn hi/lo (reused as AO hi/lo), W hi/lo x4, Kp, Vp  = 16 MB
  unsigned short* qnh = (unsigned short*)d_ws;
  unsigned short* qnl = qnh + (size_t)NTOK * DMODEL;
  unsigned short* Wqh = qnl + (size_t)NTOK * DMODEL;
  unsigned short* Wql = Wqh + DMODEL * DMODEL;
  unsigned short* Wkh = Wql + DMODEL * DMODEL;
  unsigned short* Wkl = Wkh + DMODEL * DMODEL;
  unsigned short* Wvh = Wkl + DMODEL * DMODEL;
  unsigned short* Wvl = Wvh + DMODEL * DMODEL;
  unsigned short* Wfh = Wvl + DMODEL * DMODEL;
  unsigned short* Wfl = Wfh + DMODEL * DMODEL;
  float* Kp = (float*)(Wfl + DMODEL * DMODEL);
  float* Vp = Kp + (size_t)NTOK * DMODEL;
  unsigned short* AOh = qnh;   // qn dead after proj
  unsigned short* AOl = qnl;

  ln_kernel<<<dim3(NTOK), dim3(256), 0, stream>>>(q, ln_g, ln_b, qnh, qnl);
  conv_kernel<<<dim3(1024, 6), dim3(256), 0, stream>>>(k, v, Wq, Wk, Wv, Wfc,
      kh, kl, vh, vl, Wqh, Wql, Wkh, Wkl, Wvh, Wvl, Wfh, Wfl);
  proj_mfma<<<dim3(8, 32, 3), dim3(256), 0, stream>>>(qnh, qnl, kh, kl, vh, vl,
      Wqh, Wql, Wkh, Wkl, Wvh, Wvl, Qp, Kp, Vp);
  attn2_kernel<<<dim3(8, 64, 4), dim3(256), 0, stream>>>(Qp, Kp, Vp, sim, attn, AOh, AOl);
  fc_mfma<<<dim3(8, 32, 1), dim3(256), 0, stream>>>(AOh, AOl, Wfh, Wfl, bfc, q, out);
}

// Round 6
// 566.330 us; speedup vs baseline: 1.4713x; 1.0177x over previous
//
#include <hip/hip_runtime.h>

#define DMODEL 512
#define LSEQ   512
#define BATCH  4
#define NTOK   2048   // BATCH*LSEQ

typedef __attribute__((ext_vector_type(8))) short bf8;
typedef __attribute__((ext_vector_type(4))) float f4;
typedef __attribute__((ext_vector_type(4))) unsigned short us4;
typedef __attribute__((ext_vector_type(8))) unsigned short us8;

__device__ __forceinline__ unsigned short bf16_rne(float f) {
  unsigned int u = __float_as_uint(f);
  u += 0x7FFFu + ((u >> 16) & 1u);
  return (unsigned short)(u >> 16);
}
__device__ __forceinline__ void split2(float f, unsigned short& h, unsigned short& l) {
  unsigned short hh = bf16_rne(f);
  float fh = __uint_as_float(((unsigned int)hh) << 16);
  h = hh;
  l = bf16_rne(f - fh);
}

// ---------------- LayerNorm over q -> bf16 hi/lo ----------------
__global__ __launch_bounds__(256) void ln_kernel(const float* __restrict__ q,
    const float* __restrict__ gamma, const float* __restrict__ beta,
    unsigned short* __restrict__ qh, unsigned short* __restrict__ qlo) {
  int row = blockIdx.x;
  const float* x = q + (size_t)row * DMODEL;
  int t = threadIdx.x;
  float v0 = x[t];
  float v1 = x[t + 256];
  float s  = v0 + v1;
  float ss = v0 * v0 + v1 * v1;
  #pragma unroll
  for (int o = 32; o >= 1; o >>= 1) {
    s  += __shfl_down(s, o);
    ss += __shfl_down(ss, o);
  }
  __shared__ float ls[4], lss[4];
  __shared__ float smu, srstd;
  int wid = t >> 6, lane = t & 63;
  if (lane == 0) { ls[wid] = s; lss[wid] = ss; }
  __syncthreads();
  if (t == 0) {
    float S  = ls[0] + ls[1] + ls[2] + ls[3];
    float SS = lss[0] + lss[1] + lss[2] + lss[3];
    float mu  = S * (1.0f / DMODEL);
    float var = SS * (1.0f / DMODEL) - mu * mu;
    smu = mu;
    srstd = rsqrtf(var + 1e-6f);
  }
  __syncthreads();
  float mu = smu, rstd = srstd;
  float n0 = (v0 - mu) * rstd * gamma[t]       + beta[t];
  float n1 = (v1 - mu) * rstd * gamma[t + 256] + beta[t + 256];
  unsigned short h, l;
  size_t base = (size_t)row * DMODEL;
  split2(n0, h, l); qh[base + t] = h;       qlo[base + t] = l;
  split2(n1, h, l); qh[base + t + 256] = h; qlo[base + t + 256] = l;
}

// ---------------- fp32 -> bf16 hi/lo converter (k, v, 4 weight mats) ----------------
__global__ __launch_bounds__(256) void conv_kernel(
    const float* __restrict__ k, const float* __restrict__ v,
    const float* __restrict__ Wq, const float* __restrict__ Wk,
    const float* __restrict__ Wv, const float* __restrict__ Wf,
    unsigned short* __restrict__ kh, unsigned short* __restrict__ kl,
    unsigned short* __restrict__ vh, unsigned short* __restrict__ vl,
    unsigned short* __restrict__ Wqh, unsigned short* __restrict__ Wql,
    unsigned short* __restrict__ Wkh, unsigned short* __restrict__ Wkl,
    unsigned short* __restrict__ Wvh, unsigned short* __restrict__ Wvl,
    unsigned short* __restrict__ Wfh, unsigned short* __restrict__ Wfl) {
  const float* src; unsigned short* dh; unsigned short* dl; int n;
  switch (blockIdx.y) {
    case 0:  src = k;  dh = kh;  dl = kl;  n = NTOK * DMODEL; break;
    case 1:  src = v;  dh = vh;  dl = vl;  n = NTOK * DMODEL; break;
    case 2:  src = Wq; dh = Wqh; dl = Wql; n = DMODEL * DMODEL; break;
    case 3:  src = Wk; dh = Wkh; dl = Wkl; n = DMODEL * DMODEL; break;
    case 4:  src = Wv; dh = Wvh; dl = Wvl; n = DMODEL * DMODEL; break;
    default: src = Wf; dh = Wfh; dl = Wfl; n = DMODEL * DMODEL; break;
  }
  int idx = blockIdx.x * 1024 + threadIdx.x * 4;
  if (idx >= n) return;
  float4 f = *(const float4*)(src + idx);
  us4 oh, ol;
  unsigned short h, l;
  split2(f.x, h, l); oh[0] = h; ol[0] = l;
  split2(f.y, h, l); oh[1] = h; ol[1] = l;
  split2(f.z, h, l); oh[2] = h; ol[2] = l;
  split2(f.w, h, l); oh[3] = h; ol[3] = l;
  *(us4*)(dh + idx) = oh;
  *(us4*)(dl + idx) = ol;
}

// ---------------- bf16x3 MFMA GEMM: C[M,N] = A[M,K] * W[N,K]^T ----------------
// block 256 = 4 waves (2x2), wave tile 32x32 via 2x2 of 16x16x32 MFMA. K=512.
__device__ __forceinline__ void mfma_gemm_body(
    const unsigned short* __restrict__ Ah, const unsigned short* __restrict__ Al,
    const unsigned short* __restrict__ Wh, const unsigned short* __restrict__ Wl,
    float* __restrict__ C, const float* __restrict__ bias, const float* __restrict__ resid) {
  const int t = threadIdx.x;
  const int w = t >> 6, lane = t & 63;
  const int wm = w >> 1, wn = w & 1;
  const int r0 = blockIdx.y * 64 + wm * 32;
  const int c0 = blockIdx.x * 64 + wn * 32;
  const int lr = lane & 15, quad = lane >> 4;
  f4 acc[2][2] = {};
  for (int k0 = 0; k0 < DMODEL; k0 += 32) {
    const int ko = k0 + quad * 8;
    bf8 ah[2], al[2], bh[2], bl[2];
    #pragma unroll
    for (int mi = 0; mi < 2; mi++) {
      const size_t off = (size_t)(r0 + mi * 16 + lr) * DMODEL + ko;
      ah[mi] = *(const bf8*)(Ah + off);
      al[mi] = *(const bf8*)(Al + off);
    }
    #pragma unroll
    for (int ni = 0; ni < 2; ni++) {
      const size_t off = (size_t)(c0 + ni * 16 + lr) * DMODEL + ko;
      bh[ni] = *(const bf8*)(Wh + off);
      bl[ni] = *(const bf8*)(Wl + off);
    }
    #pragma unroll
    for (int mi = 0; mi < 2; mi++)
      #pragma unroll
      for (int ni = 0; ni < 2; ni++) {
        acc[mi][ni] = __builtin_amdgcn_mfma_f32_16x16x32_bf16(al[mi], bh[ni], acc[mi][ni], 0, 0, 0);
        acc[mi][ni] = __builtin_amdgcn_mfma_f32_16x16x32_bf16(ah[mi], bl[ni], acc[mi][ni], 0, 0, 0);
        acc[mi][ni] = __builtin_amdgcn_mfma_f32_16x16x32_bf16(ah[mi], bh[ni], acc[mi][ni], 0, 0, 0);
      }
  }
  #pragma unroll
  for (int mi = 0; mi < 2; mi++)
    #pragma unroll
    for (int ni = 0; ni < 2; ni++)
      #pragma unroll
      for (int r = 0; r < 4; r++) {
        int row = r0 + mi * 16 + quad * 4 + r;   // C/D: col=lane&15, row=quad*4+reg (m89)
        int col = c0 + ni * 16 + lr;
        float o = acc[mi][ni][r];
        if (bias)  o += bias[col];
        if (resid) o += resid[(size_t)row * DMODEL + col];
        C[(size_t)row * DMODEL + col] = o;
      }
}

__global__ __launch_bounds__(256) void proj_mfma(
    const unsigned short* __restrict__ qnh, const unsigned short* __restrict__ qnl,
    const unsigned short* __restrict__ kh, const unsigned short* __restrict__ kl,
    const unsigned short* __restrict__ vh, const unsigned short* __restrict__ vl,
    const unsigned short* __restrict__ Wqh, const unsigned short* __restrict__ Wql,
    const unsigned short* __restrict__ Wkh, const unsigned short* __restrict__ Wkl,
    const unsigned short* __restrict__ Wvh, const unsigned short* __restrict__ Wvl,
    float* __restrict__ Qp, float* __restrict__ Kp, float* __restrict__ Vp) {
  const unsigned short *Ah, *Al, *Wh, *Wl; float* C;
  if (blockIdx.z == 0)      { Ah = qnh; Al = qnl; Wh = Wqh; Wl = Wql; C = Qp; }
  else if (blockIdx.z == 1) { Ah = kh;  Al = kl;  Wh = Wkh; Wl = Wkl; C = Kp; }
  else                      { Ah = vh;  Al = vl;  Wh = Wvh; Wl = Wvl; C = Vp; }
  mfma_gemm_body(Ah, Al, Wh, Wl, C, nullptr, nullptr);
}

__global__ __launch_bounds__(256) void fc_mfma(
    const unsigned short* __restrict__ AOh, const unsigned short* __restrict__ AOl,
    const unsigned short* __restrict__ Wfh, const unsigned short* __restrict__ Wfl,
    const float* __restrict__ bfc, const float* __restrict__ resid,
    float* __restrict__ out) {
  mfma_gemm_body(AOh, AOl, Wfh, Wfl, out, bfc, resid);
}

// Multi-value butterfly reduce: 8 per-lane feature accumulators -> full 64-lane sums
// in 10 shuffles. Combine order per feature is the identical xor 1,2,4,8,16,32 ladder
// as a per-feature reduce -> bit-identical results (validated Rounds 1/3/4).
// Final: every lane holds the sum for feature f = ((lane&1)<<2)|(lane&2)|((lane>>2)&1).
__device__ __forceinline__ float pv_reduce8(float pv[8], int lane) {
  #pragma unroll
  for (int i = 0; i < 4; i++) {
    float sendv = (lane & 1) ? pv[i] : pv[i + 4];
    float recv = __shfl_xor(sendv, 1);
    pv[i] = ((lane & 1) ? pv[i + 4] : pv[i]) + recv;
  }
  #pragma unroll
  for (int i = 0; i < 2; i++) {
    float sendv = (lane & 2) ? pv[i] : pv[i + 2];
    float recv = __shfl_xor(sendv, 2);
    pv[i] = ((lane & 2) ? pv[i + 2] : pv[i]) + recv;
  }
  {
    float sendv = (lane & 4) ? pv[0] : pv[1];
    float recv = __shfl_xor(sendv, 4);
    pv[0] = ((lane & 4) ? pv[1] : pv[0]) + recv;
  }
  pv[0] += __shfl_xor(pv[0], 8);
  pv[0] += __shfl_xor(pv[0], 16);
  pv[0] += __shfl_xor(pv[0], 32);
  return pv[0];
}

// ---------------- attention per (b, dk): K in regs, V in LDS, vectorized sim/attn ----------------
// grid (8 qtiles x 64 dk x 4 b); block 256 = 4 waves; wave handles 16 q rows.
// Round-5 change: software-prefetch sim rows + Q fragments for qi+1 (issued one
// iteration early, SAME addresses/order/widths) so load latency hides under the
// previous iteration's softmax/PV chain. Everything else identical to the
// verified 576us kernel.
__global__ __launch_bounds__(256, 3) void attn2_kernel(
    const float* __restrict__ Qp, const float* __restrict__ Kp, const float* __restrict__ Vp,
    const float* __restrict__ sim, float* __restrict__ attn_out,
    unsigned short* __restrict__ AOh, unsigned short* __restrict__ AOl) {
  __shared__ float Vt[8][516];   // padded: conflict-free staging writes, aligned b128 reads
  __shared__ float Qs[64][8];
  __shared__ float Rp[4][8];     // per-wave PV repack (wave-synchronous)
  const int qt = blockIdx.x, dk = blockIdx.y, b = blockIdx.z;
  const int t = threadIdx.x;
  const float* Vbase = Vp + (size_t)b * LSEQ * DMODEL + dk * 8;
  #pragma unroll
  for (int it = 0; it < 16; it++) {
    int idx = it * 256 + t;
    int l = idx >> 3, j = idx & 7;
    Vt[j][l] = Vbase[(size_t)l * DMODEL + j];
  }
  const float* Qbase = Qp + ((size_t)b * LSEQ + qt * 64) * DMODEL + dk * 8;
  #pragma unroll
  for (int it = 0; it < 2; it++) {
    int idx = it * 256 + t;
    int l = idx >> 3, j = idx & 7;
    Qs[l][j] = Qbase[(size_t)l * DMODEL + j];
  }
  const int lane = t & 63, w = t >> 6;
  const float* Kbase = Kp + (size_t)b * LSEQ * DMODEL + dk * 8;
  float Kr[2][8][4];                         // [chunk][feature][sub]: kp = c*256 + lane*4 + s
  #pragma unroll
  for (int c = 0; c < 2; c++)
    #pragma unroll
    for (int s = 0; s < 4; s++) {
      const float* kr = Kbase + (size_t)(c * 256 + lane * 4 + s) * DMODEL;
      float4 a  = *(const float4*)kr;
      float4 bb = *(const float4*)(kr + 4);
      Kr[c][0][s] = a.x;  Kr[c][1][s] = a.y;  Kr[c][2][s] = a.z;  Kr[c][3][s] = a.w;
      Kr[c][4][s] = bb.x; Kr[c][5][s] = bb.y; Kr[c][6][s] = bb.z; Kr[c][7][s] = bb.w;
    }
  __syncthreads();

  // prologue: loads for qi=0
  const size_t base0 = (((size_t)(b * 64 + dk) * LSEQ) + (qt * 64 + w * 16)) * LSEQ;
  f4 sv0 = *(const f4*)(sim + base0 + lane * 4);
  f4 sv1 = *(const f4*)(sim + base0 + 256 + lane * 4);
  f4 qr0 = *(const f4*)&Qs[w * 16][0];
  f4 qr1 = *(const f4*)&Qs[w * 16][4];

  for (int qi = 0; qi < 16; qi++) {
    const int ql = w * 16 + qi;
    const int q  = qt * 64 + ql;
    const size_t rowoff = base0 + (size_t)qi * LSEQ;
    // prefetch next iteration's sim rows + Q fragments (same addresses as before,
    // just issued one iteration early; consumed after ~full body of compute)
    f4 nsv0, nsv1, nqr0, nqr1;
    if (qi < 15) {
      nsv0 = *(const f4*)(sim + rowoff + LSEQ + lane * 4);
      nsv1 = *(const f4*)(sim + rowoff + LSEQ + 256 + lane * 4);
      nqr0 = *(const f4*)&Qs[ql + 1][0];
      nqr1 = *(const f4*)&Qs[ql + 1][4];
    }
    float svf[2][4] = {{sv0[0], sv0[1], sv0[2], sv0[3]}, {sv1[0], sv1[1], sv1[2], sv1[3]}};
    float qreg[8] = {qr0[0], qr0[1], qr0[2], qr0[3], qr1[0], qr1[1], qr1[2], qr1[3]};
    float sc[2][4];
    #pragma unroll
    for (int c = 0; c < 2; c++)
      #pragma unroll
      for (int s = 0; s < 4; s++) {
        float d = 0.0f;
        #pragma unroll
        for (int j = 0; j < 8; j++) d = fmaf(qreg[j], Kr[c][j][s], d);
        sc[c][s] = fmaf(d, 0.125f, svf[c][s]);
      }
    float m = sc[0][0];
    #pragma unroll
    for (int c = 0; c < 2; c++)
      #pragma unroll
      for (int s = 0; s < 4; s++) m = fmaxf(m, sc[c][s]);
    #pragma unroll
    for (int o = 1; o < 64; o <<= 1) m = fmaxf(m, __shfl_xor(m, o));
    float p[2][4]; float sum = 0.0f;
    #pragma unroll
    for (int c = 0; c < 2; c++)
      #pragma unroll
      for (int s = 0; s < 4; s++) { p[c][s] = __expf(sc[c][s] - m); sum += p[c][s]; }
    #pragma unroll
    for (int o = 1; o < 64; o <<= 1) sum += __shfl_xor(sum, o);
    const float r = 1.0f / sum;
    #pragma unroll
    for (int c = 0; c < 2; c++)
      #pragma unroll
      for (int s = 0; s < 4; s++) p[c][s] *= r;
    float4 st0 = {p[0][0], p[0][1], p[0][2], p[0][3]};
    float4 st1 = {p[1][0], p[1][1], p[1][2], p[1][3]};
    *(float4*)(attn_out + rowoff + lane * 4) = st0;
    *(float4*)(attn_out + rowoff + 256 + lane * 4) = st1;
    // PV
    float pv[8];
    #pragma unroll
    for (int j = 0; j < 8; j++) {
      float acc = 0.0f;
      #pragma unroll
      for (int c = 0; c < 2; c++) {
        float4 vv = *(const float4*)&Vt[j][c * 256 + lane * 4];
        acc = fmaf(p[c][0], vv.x, acc);
        acc = fmaf(p[c][1], vv.y, acc);
        acc = fmaf(p[c][2], vv.z, acc);
        acc = fmaf(p[c][3], vv.w, acc);
      }
      pv[j] = acc;
    }
    // 10-shuffle butterfly (bit-identical sums) + in-wave LDS repack
    float red = pv_reduce8(pv, lane);
    if (lane < 8)
      Rp[w][((lane & 1) << 2) | (lane & 2) | ((lane >> 2) & 1)] = red;
    __builtin_amdgcn_wave_barrier();   // in-wave LDS write->read ordering fence
    if (lane < 2) {
      us8 ov;
      #pragma unroll
      for (int j = 0; j < 8; j++) {
        unsigned short h, l;
        split2(Rp[w][j], h, l);
        ov[j] = (lane == 0) ? h : l;
      }
      unsigned short* dst = ((lane == 0) ? AOh : AOl) + ((size_t)b * LSEQ + q) * DMODEL + dk * 8;
      *(us8*)dst = ov;
    }
    if (qi < 15) { sv0 = nsv0; sv1 = nsv1; qr0 = nqr0; qr1 = nqr1; }
  }
}

extern "C" void kernel_launch(void* const* d_in, const int* in_sizes, int n_in,
                              void* d_out, int out_size, void* d_ws, size_t ws_size,
                              hipStream_t stream) {
  const float* q    = (const float*)d_in[0];
  const float* k    = (const float*)d_in[1];
  const float* v    = (const float*)d_in[2];
  const float* sim  = (const float*)d_in[3];
  const float* Wq   = (const float*)d_in[4];
  const float* Wk   = (const float*)d_in[5];
  const float* Wv   = (const float*)d_in[6];
  const float* Wfc  = (const float*)d_in[7];
  const float* bfc  = (const float*)d_in[8];
  const float* ln_g = (const float*)d_in[9];
  const float* ln_b = (const float*)d_in[10];

  float* out  = (float*)d_out;                          // [B,L,DM] (also holds Qp until fc)
  float* attn = out + (size_t)NTOK * DMODEL;            // [B,64,L,L]

  // scratch inside attn region (dead before attn2 writes it): k/v bf16 hi/lo
  unsigned short* kh = (unsigned short*)attn;
  unsigned short* kl = kh + (size_t)NTOK * DMODEL;
  unsigned short* vh = kl + (size_t)NTOK * DMODEL;
  unsigned short* vl = vh + (size_t)NTOK * DMODEL;
  float* Qp = out;                                      // out region reused; fc overwrites at end

  // ws layout: qn hi/lo (reused as AO hi/lo), W hi/lo x4, Kp, Vp  = 16 MB
  unsigned short* qnh = (unsigned short*)d_ws;
  unsigned short* qnl = qnh + (size_t)NTOK * DMODEL;
  unsigned short* Wqh = qnl + (size_t)NTOK * DMODEL;
  unsigned short* Wql = Wqh + DMODEL * DMODEL;
  unsigned short* Wkh = Wql + DMODEL * DMODEL;
  unsigned short* Wkl = Wkh + DMODEL * DMODEL;
  unsigned short* Wvh = Wkl + DMODEL * DMODEL;
  unsigned short* Wvl = Wvh + DMODEL * DMODEL;
  unsigned short* Wfh = Wvl + DMODEL * DMODEL;
  unsigned short* Wfl = Wfh + DMODEL * DMODEL;
  float* Kp = (float*)(Wfl + DMODEL * DMODEL);
  float* Vp = Kp + (size_t)NTOK * DMODEL;
  unsigned short* AOh = qnh;   // qn dead after proj
  unsigned short* AOl = qnl;

  ln_kernel<<<dim3(NTOK), dim3(256), 0, stream>>>(q, ln_g, ln_b, qnh, qnl);
  conv_kernel<<<dim3(1024, 6), dim3(256), 0, stream>>>(k, v, Wq, Wk, Wv, Wfc,
      kh, kl, vh, vl, Wqh, Wql, Wkh, Wkl, Wvh, Wvl, Wfh, Wfl);
  proj_mfma<<<dim3(8, 32, 3), dim3(256), 0, stream>>>(qnh, qnl, kh, kl, vh, vl,
      Wqh, Wql, Wkh, Wkl, Wvh, Wvl, Qp, Kp, Vp);
  attn2_kernel<<<dim3(8, 64, 4), dim3(256), 0, stream>>>(Qp, Kp, Vp, sim, attn, AOh, AOl);
  fc_mfma<<<dim3(8, 32, 1), dim3(256), 0, stream>>>(AOh, AOl, Wfh, Wfl, bfc, q, out);
}